// Round 4
// baseline (33.798 us; speedup 1.0000x reference)
//
#include <hip/hip_runtime.h>

#define NGRID 2048
#define BATCH 4
#define CIN   16
#define COUT  32
#define NCTX  256
#define NOUT  1024
#define OPW   4                      // targets per block
#define WAVES 4                      // waves per block; wave w owns grid chunk w*512..w*512+511
#define NBLK  (BATCH * NOUT / OPW)   // 1024 blocks x 256 threads

__device__ __forceinline__ float fexp2(float x) {
#if __has_builtin(__builtin_amdgcn_exp2f)
    return __builtin_amdgcn_exp2f(x);
#else
    return exp2f(x);
#endif
}

__global__ __launch_bounds__(256) void conv_decoder_fused(
        const float* __restrict__ r,      // (B, CIN, NGRID)
        const float* __restrict__ xc,     // (B, NCTX)
        const float* __restrict__ xt,     // (B, NOUT)
        const float* __restrict__ sigma,  // (CIN)
        const float* __restrict__ W,      // (CIN, COUT)
        const float* __restrict__ bias,   // (COUT)
        float* __restrict__ out) {        // (B, NOUT, COUT)
    const int tid  = threadIdx.x;
    const int lane = tid & 63;
    const int wv   = tid >> 6;
    const int blk  = blockIdx.x;
    const int b    = blk >> 8;           // NOUT/OPW = 256 groups per batch
    const int og   = blk & 255;

    // ---- cooperative block-wide min/max over xc (1024 f) + xt (4096 f) ----
    float mn, mx;
    {
        float4 v = *reinterpret_cast<const float4*>(xc + tid * 4);
        mn = fminf(fminf(v.x, v.y), fminf(v.z, v.w));
        mx = fmaxf(fmaxf(v.x, v.y), fmaxf(v.z, v.w));
        #pragma unroll
        for (int k = 0; k < 4; ++k) {
            float4 u = *reinterpret_cast<const float4*>(xt + (k * 256 + tid) * 4);
            mn = fminf(mn, fminf(fminf(u.x, u.y), fminf(u.z, u.w)));
            mx = fmaxf(mx, fmaxf(fmaxf(u.x, u.y), fmaxf(u.z, u.w)));
        }
        #pragma unroll
        for (int off = 32; off; off >>= 1) {
            mn = fminf(mn, __shfl_xor(mn, off));
            mx = fmaxf(mx, __shfl_xor(mx, off));
        }
    }
    __shared__ float smn[WAVES], smx[WAVES];
    __shared__ float part[WAVES][64];
    if (lane == 0) { smn[wv] = mn; smx[wv] = mx; }
    __syncthreads();
    mn = fminf(fminf(smn[0], smn[1]), fminf(smn[2], smn[3]));
    mx = fmaxf(fmaxf(smx[0], smx[1]), fmaxf(smx[2], smx[3]));
    const float xmin = mn - 0.1f;
    const float step = ((mx + 0.1f) - xmin) * (1.0f / (float)(NGRID - 1));

    // ---- per-channel exponent coefficients; uniformity check ----
    const float LOG2E = 1.4426950408889634f;
    float a2[CIN];
    #pragma unroll
    for (int c = 0; c < CIN; ++c) {
        float s = sigma[c];
        a2[c] = -0.5f * LOG2E * fexp2(-2.0f * LOG2E * s);  // exp2(a2*d^2) == exp(-0.5 d^2/scale^2)
    }
    bool uni = true;
    #pragma unroll
    for (int c = 1; c < CIN; ++c) uni = uni && (a2[c] == a2[0]);

    float x[OPW];
    #pragma unroll
    for (int j = 0; j < OPW; ++j) x[j] = xt[b * NOUT + og * OPW + j];

    float acc[OPW * CIN];   // value v = j*16 + c (partial over this wave's 512 grid points)
    #pragma unroll
    for (int v = 0; v < OPW * CIN; ++v) acc[v] = 0.0f;

    const float* rb = r + (size_t)b * (CIN * NGRID);

    if (uni) {
        const float a = a2[0];           // a <= 0
        const float s = sqrtf(-a);       // weight = exp2(-(s*g - s*x)^2)
        float sx[OPW];
        #pragma unroll
        for (int j = 0; j < OPW; ++j) sx[j] = s * x[j];

        #pragma unroll 1
        for (int k = 0; k < 2; ++k) {    // 2 iterations of 256 points per wave
            const int i0 = wv * 512 + k * 256 + lane * 4;
            float wgt[OPW][4];
            #pragma unroll
            for (int p = 0; p < 4; ++p) {
                float sg = s * (xmin + step * (float)(i0 + p));
                #pragma unroll
                for (int j = 0; j < OPW; ++j) {
                    float d = sg - sx[j];
                    wgt[j][p] = fexp2(-(d * d));
                }
            }
            #pragma unroll
            for (int h = 0; h < 2; ++h) {          // two batches of 8 channels
                float4 rv[8];
                #pragma unroll
                for (int c8 = 0; c8 < 8; ++c8)
                    rv[c8] = *reinterpret_cast<const float4*>(rb + (h * 8 + c8) * NGRID + i0);
                #pragma unroll
                for (int c8 = 0; c8 < 8; ++c8) {
                    const int c = h * 8 + c8;
                    #pragma unroll
                    for (int j = 0; j < OPW; ++j) {
                        acc[j * CIN + c] += rv[c8].x * wgt[j][0];
                        acc[j * CIN + c] += rv[c8].y * wgt[j][1];
                        acc[j * CIN + c] += rv[c8].z * wgt[j][2];
                        acc[j * CIN + c] += rv[c8].w * wgt[j][3];
                    }
                }
            }
        }
    } else {
        // generic fallback: per-channel exponents (correct for any sigma)
        #pragma unroll 1
        for (int k = 0; k < 2; ++k) {
            const int i0 = wv * 512 + k * 256 + lane * 4;
            float d2[OPW][4];
            #pragma unroll
            for (int p = 0; p < 4; ++p) {
                float g = xmin + step * (float)(i0 + p);
                #pragma unroll
                for (int j = 0; j < OPW; ++j) {
                    float d = g - x[j];
                    d2[j][p] = d * d;
                }
            }
            #pragma unroll
            for (int c = 0; c < CIN; ++c) {
                float4 rv = *reinterpret_cast<const float4*>(rb + c * NGRID + i0);
                float a = a2[c];
                #pragma unroll
                for (int j = 0; j < OPW; ++j) {
                    acc[j * CIN + c] += rv.x * fexp2(a * d2[j][0]);
                    acc[j * CIN + c] += rv.y * fexp2(a * d2[j][1]);
                    acc[j * CIN + c] += rv.z * fexp2(a * d2[j][2]);
                    acc[j * CIN + c] += rv.w * fexp2(a * d2[j][3]);
                }
            }
        }
    }

    // ---- 6-stage value-routing fold: lane L ends with this wave's total of value L ----
    #pragma unroll
    for (int st = 0; st < 6; ++st) {
        const int off = 32 >> st;
        const bool hi = (lane & off) != 0;
        #pragma unroll
        for (int v = 0; v < (32 >> st); ++v) {
            float keep = hi ? acc[v + (32 >> st)] : acc[v];
            float send = hi ? acc[v] : acc[v + (32 >> st)];
            acc[v] = keep + __shfl_xor(send, off);
        }
    }

    // ---- cross-wave combine + per-wave epilogue (wave wv handles target wv) ----
    part[wv][lane] = acc[0];
    __syncthreads();
    float tot = part[0][lane] + part[1][lane] + part[2][lane] + part[3][lane];
    // wave wv needs values v = wv*16 + c, which live on lanes wv*16+c of every wave
    float z[CIN];
    #pragma unroll
    for (int c = 0; c < CIN; ++c)
        z[c] = __shfl(tot, wv * 16 + c);

    if (lane < COUT) {
        float o = bias[lane];
        #pragma unroll
        for (int c = 0; c < CIN; ++c)
            o += z[c] * W[c * COUT + lane];
        out[((size_t)b * NOUT + og * OPW + wv) * COUT + lane] = o;
    }
}

extern "C" void kernel_launch(void* const* d_in, const int* in_sizes, int n_in,
                              void* d_out, int out_size, void* d_ws, size_t ws_size,
                              hipStream_t stream) {
    const float* r  = (const float*)d_in[0];  // (4,16,2048)
    const float* xc = (const float*)d_in[1];  // (4,256,1)
    // d_in[2] = y_context — unused by the reference
    const float* xt = (const float*)d_in[3];  // (4,1024,1)
    const float* sg = (const float*)d_in[4];  // (16)
    const float* W  = (const float*)d_in[5];  // (16,32)
    const float* bs = (const float*)d_in[6];  // (32)
    float* out = (float*)d_out;               // (4,1024,32) f32

    // PROBE ROUND: launch the identical kernel twice back-to-back.
    // bench_dur ~= F + 2K (R3 measured F + K = 19.5 us). The delta vs R3
    // directly measures the steady-state kernel time K, disambiguating
    // "launch/replay overhead floor" (H1) from "kernel still latency-bound" (H2).
    // Deterministic: second launch rewrites identical values.
    conv_decoder_fused<<<NBLK, 256, 0, stream>>>(r, xc, xt, sg, W, bs, out);
    conv_decoder_fused<<<NBLK, 256, 0, stream>>>(r, xc, xt, sg, W, bs, out);
}

// Round 5
// 24.579 us; speedup vs baseline: 1.3751x; 1.3751x over previous
//
#include <hip/hip_runtime.h>

#define NGRID  2048
#define BATCH  4
#define CIN    16
#define COUT   32
#define NCTX   256
#define NOUT   1024
#define TPB    16                      // targets per block (4 per wave x 4 waves)
#define CHUNK  256                     // grid points staged per chunk
#define NCHUNK (NGRID / CHUNK)         // 8
#define NBLK   (BATCH * NOUT / TPB)    // 256 blocks = 1 per CU

typedef float v2f __attribute__((ext_vector_type(2)));

__device__ __forceinline__ float fexp2(float x) {
#if __has_builtin(__builtin_amdgcn_exp2f)
    return __builtin_amdgcn_exp2f(x);
#else
    return exp2f(x);
#endif
}

// 256 threads = 4 waves. Block handles 16 targets x full grid for one batch.
// r chunk (16ch x 256pts, 16KB) double-buffered in LDS; each wave computes its
// own 4 targets over every chunk. Packed f32 FMA for the channel accumulation.
__global__ __launch_bounds__(256, 1) void conv_decoder_fused(
        const float* __restrict__ r,      // (B, CIN, NGRID)
        const float* __restrict__ xc,     // (B, NCTX)
        const float* __restrict__ xt,     // (B, NOUT)
        const float* __restrict__ sigma,  // (CIN)
        const float* __restrict__ W,      // (CIN, COUT)
        const float* __restrict__ bias,   // (COUT)
        float* __restrict__ out) {        // (B, NOUT, COUT)
    const int tid  = threadIdx.x;
    const int lane = tid & 63;
    const int wv   = tid >> 6;
    const int blk  = blockIdx.x;
    const int b    = blk >> 6;            // 64 target-groups per batch
    const int tg0  = (blk & 63) * TPB;    // first target of block

    __shared__ float sbuf[2][CIN][CHUNK]; // 2 x 16 KB
    __shared__ float smn[4], smx[4];

    const float* rb = r + (size_t)b * (CIN * NGRID);

    // ---- issue chunk-0 stage loads early (latency hides under minmax) ----
    float4 st[4];
    #pragma unroll
    for (int q = 0; q < 4; ++q)
        st[q] = *reinterpret_cast<const float4*>(rb + (wv * 4 + q) * NGRID + lane * 4);

    // ---- cooperative block-wide min/max over xc (1024 f) + xt (4096 f) ----
    float mn, mx;
    {
        float4 v = *reinterpret_cast<const float4*>(xc + tid * 4);
        mn = fminf(fminf(v.x, v.y), fminf(v.z, v.w));
        mx = fmaxf(fmaxf(v.x, v.y), fmaxf(v.z, v.w));
        #pragma unroll
        for (int k = 0; k < 4; ++k) {
            float4 u = *reinterpret_cast<const float4*>(xt + (k * 256 + tid) * 4);
            mn = fminf(mn, fminf(fminf(u.x, u.y), fminf(u.z, u.w)));
            mx = fmaxf(mx, fmaxf(fmaxf(u.x, u.y), fmaxf(u.z, u.w)));
        }
        #pragma unroll
        for (int off = 32; off; off >>= 1) {
            mn = fminf(mn, __shfl_xor(mn, off));
            mx = fmaxf(mx, __shfl_xor(mx, off));
        }
    }
    if (lane == 0) { smn[wv] = mn; smx[wv] = mx; }
    __syncthreads();
    mn = fminf(fminf(smn[0], smn[1]), fminf(smn[2], smn[3]));
    mx = fmaxf(fmaxf(smx[0], smx[1]), fmaxf(smx[2], smx[3]));
    const float xmin = mn - 0.1f;
    const float step = ((mx + 0.1f) - xmin) * (1.0f / (float)(NGRID - 1));

    // ---- write staged chunk 0 ----
    #pragma unroll
    for (int q = 0; q < 4; ++q)
        *reinterpret_cast<float4*>(&sbuf[0][wv * 4 + q][lane * 4]) = st[q];

    // ---- per-channel exponent coefficients; uniformity check ----
    const float LOG2E = 1.4426950408889634f;
    float a2[CIN];
    #pragma unroll
    for (int c = 0; c < CIN; ++c)
        a2[c] = -0.5f * LOG2E * fexp2(-2.0f * LOG2E * sigma[c]);
    bool uni = true;
    #pragma unroll
    for (int c = 1; c < CIN; ++c) uni = uni && (a2[c] == a2[0]);

    float x4[4];
    #pragma unroll
    for (int j = 0; j < 4; ++j) x4[j] = xt[b * NOUT + tg0 + wv * 4 + j];

    const float s     = sqrtf(-a2[0]);    // uniform path: w = exp2(-(s*g - s*x)^2)
    const float sxm   = s * xmin;
    const float sstep = s * step;
    float sx[4];
    #pragma unroll
    for (int j = 0; j < 4; ++j) sx[j] = s * x4[j];

    v2f acc[4][CIN];
    #pragma unroll
    for (int j = 0; j < 4; ++j)
        #pragma unroll
        for (int c = 0; c < CIN; ++c) acc[j][c] = 0.0f;

    __syncthreads();   // chunk 0 visible to all waves

    #pragma unroll 1
    for (int k = 0; k < NCHUNK; ++k) {
        const int cur = k & 1;
        // prefetch next chunk into registers (issue early, write late)
        float4 pf[4];
        if (k + 1 < NCHUNK) {
            #pragma unroll
            for (int q = 0; q < 4; ++q)
                pf[q] = *reinterpret_cast<const float4*>(
                    rb + (wv * 4 + q) * NGRID + (k + 1) * CHUNK + lane * 4);
        }
        const float gbase = (float)(k * CHUNK + lane * 4);
        if (uni) {
            v2f w2[4][2];
            #pragma unroll
            for (int p = 0; p < 4; ++p) {
                float sg = fmaf(sstep, gbase + (float)p, sxm);
                #pragma unroll
                for (int j = 0; j < 4; ++j) {
                    float d = sg - sx[j];
                    w2[j][p >> 1][p & 1] = fexp2(-(d * d));
                }
            }
            #pragma unroll
            for (int c = 0; c < CIN; ++c) {
                float4 rv = *reinterpret_cast<const float4*>(&sbuf[cur][c][lane * 4]);
                v2f rlo; rlo[0] = rv.x; rlo[1] = rv.y;
                v2f rhi; rhi[0] = rv.z; rhi[1] = rv.w;
                #pragma unroll
                for (int j = 0; j < 4; ++j) {
                    acc[j][c] = __builtin_elementwise_fma(rlo, w2[j][0], acc[j][c]);
                    acc[j][c] = __builtin_elementwise_fma(rhi, w2[j][1], acc[j][c]);
                }
            }
        } else {
            // generic per-channel fallback (correct for any sigma)
            float d2[4][4];
            #pragma unroll
            for (int p = 0; p < 4; ++p) {
                float g = xmin + step * (gbase + (float)p);
                #pragma unroll
                for (int j = 0; j < 4; ++j) {
                    float d = g - x4[j];
                    d2[j][p] = d * d;
                }
            }
            #pragma unroll
            for (int c = 0; c < CIN; ++c) {
                float4 rv = *reinterpret_cast<const float4*>(&sbuf[cur][c][lane * 4]);
                float rr[4] = {rv.x, rv.y, rv.z, rv.w};
                #pragma unroll
                for (int p = 0; p < 4; ++p)
                    #pragma unroll
                    for (int j = 0; j < 4; ++j)
                        acc[j][c][p & 1] += rr[p] * fexp2(a2[c] * d2[j][p]);
            }
        }
        // write prefetched chunk into the other buffer, then sync
        if (k + 1 < NCHUNK) {
            #pragma unroll
            for (int q = 0; q < 4; ++q)
                *reinterpret_cast<float4*>(&sbuf[cur ^ 1][wv * 4 + q][lane * 4]) = pf[q];
        }
        __syncthreads();
    }

    // ---- collapse float2 halves; 6-stage value-routing fold ----
    float accs[64];
    #pragma unroll
    for (int j = 0; j < 4; ++j)
        #pragma unroll
        for (int c = 0; c < CIN; ++c)
            accs[j * 16 + c] = acc[j][c][0] + acc[j][c][1];

    #pragma unroll
    for (int stg = 0; stg < 6; ++stg) {
        const int off = 32 >> stg;
        const bool hi = (lane & off) != 0;
        #pragma unroll
        for (int v = 0; v < (32 >> stg); ++v) {
            float keep = hi ? accs[v + (32 >> stg)] : accs[v];
            float send = hi ? accs[v] : accs[v + (32 >> stg)];
            accs[v] = keep + __shfl_xor(send, off);
        }
    }
    // lane L now holds the full-grid total of value L = j*16 + c (for this wave's targets)

    // ---- epilogue: each wave outputs its own 4 targets ----
    const int jo = lane >> 4;       // target within wave's group of 4
    const int co = lane & 15;
    float z[CIN];
    #pragma unroll
    for (int c = 0; c < CIN; ++c)
        z[c] = __shfl(accs[0], jo * 16 + c);

    float o0 = bias[co];
    float o1 = bias[co + 16];
    #pragma unroll
    for (int c = 0; c < CIN; ++c) {
        o0 += z[c] * W[c * COUT + co];
        o1 += z[c] * W[c * COUT + co + 16];
    }
    const size_t orow = ((size_t)b * NOUT + tg0 + wv * 4 + jo) * COUT;
    out[orow + co]      = o0;
    out[orow + co + 16] = o1;
}

extern "C" void kernel_launch(void* const* d_in, const int* in_sizes, int n_in,
                              void* d_out, int out_size, void* d_ws, size_t ws_size,
                              hipStream_t stream) {
    const float* r  = (const float*)d_in[0];  // (4,16,2048)
    const float* xc = (const float*)d_in[1];  // (4,256,1)
    // d_in[2] = y_context — unused by the reference
    const float* xt = (const float*)d_in[3];  // (4,1024,1)
    const float* sg = (const float*)d_in[4];  // (16)
    const float* W  = (const float*)d_in[5];  // (16,32)
    const float* bs = (const float*)d_in[6];  // (32)
    float* out = (float*)d_out;               // (4,1024,32) f32

    conv_decoder_fused<<<NBLK, 256, 0, stream>>>(r, xc, xt, sg, W, bs, out);
}

// Round 6
// 11.945 us; speedup vs baseline: 2.8296x; 2.0577x over previous
//
#include <hip/hip_runtime.h>
#include <hip/hip_bf16.h>

#define NGRID  2048
#define BATCH  4
#define CIN    16
#define COUT   32
#define NOUT   1024
#define NT     16                     // targets per block
#define NW     16                     // waves per block = K slices
#define KSL    (NGRID / NW)           // 128 grid points per wave
#define KSTEP  (KSL / 32)             // 4 MFMA K-steps per wave
#define NBLK   (BATCH * (NOUT / NT))  // 256 blocks

typedef short bf16x8 __attribute__((ext_vector_type(8)));
typedef float f32x4  __attribute__((ext_vector_type(4)));

__device__ __forceinline__ float fexp2(float x) {
#if __has_builtin(__builtin_amdgcn_exp2f)
    return __builtin_amdgcn_exp2f(x);
#else
    return exp2f(x);
#endif
}

union ABfrag { bf16x8 v; short2 s2[4]; };

// packed f32->bf16 (compiler emits v_cvt_pk_bf16_f32; don't hand-write asm per m240)
__device__ __forceinline__ short2 pk_bf16(float lo, float hi) {
    __hip_bfloat162 h = __float22bfloat162_rn(float2{lo, hi});
    short2 r;
    __builtin_memcpy(&r, &h, 4);
    return r;
}

// Block = (batch, 16 targets), 16 waves; wave wv owns grid K-slice [wv*128, wv*128+128).
// Uniform-sigma fast path: z = r_bf16 @ w_bf16 via mfma_f32_16x16x32_bf16
//   A lane layout: row c = lane&15, k = (lane>>4)*8 + j   (8 bf16 / lane)
//   B lane layout: col t = lane&15, k = (lane>>4)*8 + j
//   C/D (m89-verified): col t = lane&15, row c = (lane>>4)*4 + reg
// Cross-wave K-reduce via LDS, then 16->32 W matmul epilogue.
__global__ __launch_bounds__(1024) void conv_decoder_mfma(
        const float* __restrict__ r,      // (B, CIN, NGRID)
        const float* __restrict__ xc,     // (B, NCTX) = 1024 floats
        const float* __restrict__ xt,     // (B, NOUT) = 4096 floats
        const float* __restrict__ sigma,  // (CIN)
        const float* __restrict__ W,      // (CIN, COUT)
        const float* __restrict__ bias,   // (COUT)
        float* __restrict__ out) {        // (B, NOUT, COUT)
    const int tid  = threadIdx.x;
    const int lane = tid & 63;
    const int wv   = tid >> 6;            // 0..15 = K slice
    const int blk  = blockIdx.x;
    const int b    = blk >> 6;            // 64 target-groups per batch
    const int tg0  = (blk & 63) * NT;

    __shared__ float part[NW][CIN][NT];   // 16 KB
    __shared__ float zbuf[CIN][NT];       // 1 KB
    __shared__ float smn[NW], smx[NW];

    // ---- block-wide min/max over xc (1024) + xt (4096) ----
    float mn, mx;
    {
        float v = xc[tid];
        mn = v; mx = v;
        float4 u = *reinterpret_cast<const float4*>(xt + tid * 4);
        mn = fminf(mn, fminf(fminf(u.x, u.y), fminf(u.z, u.w)));
        mx = fmaxf(mx, fmaxf(fmaxf(u.x, u.y), fmaxf(u.z, u.w)));
        #pragma unroll
        for (int off = 32; off; off >>= 1) {
            mn = fminf(mn, __shfl_xor(mn, off));
            mx = fmaxf(mx, __shfl_xor(mx, off));
        }
    }
    if (lane == 0) { smn[wv] = mn; smx[wv] = mx; }
    __syncthreads();
    #pragma unroll
    for (int w2 = 0; w2 < NW; ++w2) {
        mn = fminf(mn, smn[w2]);
        mx = fmaxf(mx, smx[w2]);
    }
    const float xmin = mn - 0.1f;
    const float step = ((mx + 0.1f) - xmin) * (1.0f / (float)(NGRID - 1));

    // ---- per-channel exponent coefficients; uniformity check ----
    const float LOG2E = 1.4426950408889634f;
    float a2[CIN];
    #pragma unroll
    for (int c = 0; c < CIN; ++c)
        a2[c] = -0.5f * LOG2E * fexp2(-2.0f * LOG2E * sigma[c]);  // exp2(a2*d^2)
    bool uni = true;
    #pragma unroll
    for (int c = 1; c < CIN; ++c) uni = uni && (a2[c] == a2[0]);

    const int t  = lane & 15;             // target col (B/C) ; also channel row for A
    const int kb = lane >> 4;             // k-group
    const int wk0 = wv * KSL;
    const float xT = xt[b * NOUT + tg0 + t];
    const float* rb = r + (size_t)b * (CIN * NGRID);

    f32x4 acc = {0.0f, 0.0f, 0.0f, 0.0f};

    if (uni) {
        const float s     = sqrtf(-a2[0]);   // w = exp2(-(s*g - s*x)^2)
        const float sxm   = s * xmin;
        const float sstep = s * step;
        const float sx    = s * xT;
        const float* rrow = rb + (lane & 15) * NGRID + wk0 + kb * 8;

        #pragma unroll
        for (int kk = 0; kk < KSTEP; ++kk) {
            const int k0 = wk0 + kk * 32;
            // A fragment: 8 consecutive r f32 -> bf16
            float4 r0 = *reinterpret_cast<const float4*>(rrow + kk * 32);
            float4 r1 = *reinterpret_cast<const float4*>(rrow + kk * 32 + 4);
            ABfrag A;
            A.s2[0] = pk_bf16(r0.x, r0.y);
            A.s2[1] = pk_bf16(r0.z, r0.w);
            A.s2[2] = pk_bf16(r1.x, r1.y);
            A.s2[3] = pk_bf16(r1.z, r1.w);
            // B fragment: w[k][t], k = k0 + kb*8 + j
            float wgt[8];
            #pragma unroll
            for (int j = 0; j < 8; ++j) {
                float gi = (float)(k0 + kb * 8 + j);
                float d  = fmaf(sstep, gi, sxm) - sx;
                wgt[j] = fexp2(-(d * d));
            }
            ABfrag Bf;
            #pragma unroll
            for (int p = 0; p < 4; ++p)
                Bf.s2[p] = pk_bf16(wgt[2 * p], wgt[2 * p + 1]);
            acc = __builtin_amdgcn_mfma_f32_16x16x32_bf16(A.v, Bf.v, acc, 0, 0, 0);
        }
    } else {
        // generic per-channel-sigma fallback (f32 VALU), same C-frag layout:
        // lane computes z[c][t] for c = kb*4 + reg over its whole K-slice
        #pragma unroll 1
        for (int k = 0; k < KSL; ++k) {
            float g  = xmin + step * (float)(wk0 + k);
            float d  = g - xT;
            float d2 = d * d;
            #pragma unroll
            for (int reg = 0; reg < 4; ++reg) {
                int c = kb * 4 + reg;
                acc[reg] += rb[c * NGRID + wk0 + k] * fexp2(a2[c] * d2);
            }
        }
    }

    // ---- write C fragments; cross-wave K reduction ----
    #pragma unroll
    for (int reg = 0; reg < 4; ++reg)
        part[wv][kb * 4 + reg][t] = acc[reg];
    __syncthreads();

    if (tid < CIN * NT) {                 // 256 threads: one (c,t) each
        const int c  = tid >> 4;
        const int tt = tid & 15;
        float z = 0.0f;
        #pragma unroll
        for (int w2 = 0; w2 < NW; ++w2) z += part[w2][c][tt];
        zbuf[c][tt] = z;
    }
    __syncthreads();

    // ---- epilogue: 512 threads, one (t, cout) each ----
    if (tid < NT * COUT) {
        const int tt = tid >> 5;
        const int co = tid & 31;
        float o = bias[co];
        #pragma unroll
        for (int c = 0; c < CIN; ++c)
            o = fmaf(zbuf[c][tt], W[c * COUT + co], o);
        out[((size_t)b * NOUT + tg0 + tt) * COUT + co] = o;
    }
}

extern "C" void kernel_launch(void* const* d_in, const int* in_sizes, int n_in,
                              void* d_out, int out_size, void* d_ws, size_t ws_size,
                              hipStream_t stream) {
    const float* r  = (const float*)d_in[0];  // (4,16,2048)
    const float* xc = (const float*)d_in[1];  // (4,256,1)
    // d_in[2] = y_context — unused by the reference
    const float* xt = (const float*)d_in[3];  // (4,1024,1)
    const float* sg = (const float*)d_in[4];  // (16)
    const float* W  = (const float*)d_in[5];  // (16,32)
    const float* bs = (const float*)d_in[6];  // (32)
    float* out = (float*)d_out;               // (4,1024,32) f32

    conv_decoder_mfma<<<NBLK, 1024, 0, stream>>>(r, xc, xt, sg, W, bs, out);
}